// Round 5
// baseline (18.295 us; speedup 1.0000x reference)
//
#include <hip/hip_runtime.h>

#define BB 16
#define NN 65536
#define KK 64
#define TPB 256
#define CHUNK 512                 // elements per block: two half-chunks of 256
#define NBLK ((BB * NN) / CHUNK)  // 2048 -> 8 blocks/CU -> 100% occupancy

__device__ __forceinline__ float readlane_f(float v, int lane) {
    return __uint_as_float((unsigned)__builtin_amdgcn_readlane((int)__float_as_uint(v), lane));
}

// One tiny block: compute alpha, weights (f64), sort lags ascending, write to ws.
__global__ __launch_bounds__(KK) void setup_kernel(
    const float* __restrict__ loc, const float* __restrict__ scale,
    const float* __restrict__ eps, const int* __restrict__ lags,
    int* __restrict__ js_out, float* __restrict__ ws_out)
{
    __shared__ int   jraw[KK];
    __shared__ float wraw[KK];
    const int tid = threadIdx.x;

    double s  = (double)scale[0];
    double sp = (s > 20.0) ? s : log1p(exp(s));
    double a  = (double)loc[0] + sp * (double)eps[0];
    a = fmin(fmax(a, 0.01), 0.99);
    double c = a * exp(-lgamma(1.0 - a)) * ((double)(NN - 1) / (double)KK);

    int j = lags[tid];
    j = (j < 1) ? 1 : ((j > NN - 1) ? NN - 1 : j);
    jraw[tid] = j;
    wraw[tid] = (float)(c * exp(-(a + 1.0) * log((double)j)));
    __syncthreads();

    int rank = 0;
    for (int k = 0; k < KK; ++k) {
        const int jk = jraw[k];
        rank += (int)((jk < j) || (jk == j && k < tid));
    }
    js_out[rank] = j;
    ws_out[rank] = wraw[tid];
}

// Main kernel: no LDS, no barriers. Sorted lags/weights live in lanes of a VGPR;
// validity prefix via wave ballot; gathers use SGPR base + shared vaddr.
__global__ __launch_bounds__(TPB) void frac_deriv_kernel(
    const float* __restrict__ x,
    const int* __restrict__ js,
    const float* __restrict__ ws,
    float* __restrict__ out)
{
    const int tid = threadIdx.x;
    // Bijective XCD swizzle (2048 blocks -> 256 contiguous per XCD = 2 rows),
    // and heavy-first (large T first) within each XCD chunk to kill the tail.
    const int bid = blockIdx.x;
    const int swz = (bid & 7) * (NBLK / 8) + (bid >> 3);
    const int b   = swz >> 7;              // row [0,16)
    const int q   = 127 - (swz & 127);     // segment, heavy-first
    const int T   = q * CHUNK;

    const int   lane = tid & 63;
    const int   jv   = js[lane];           // lane m holds sorted j_m
    const float wv   = ws[lane];           // lane m holds w_m
    const int cf = __popcll(__ballot(jv <= T));               // fully-valid prefix
    const int cp = __popcll(__ballot(jv <= T + (CHUNK - 1))); // incl. straddle

    const float* __restrict__ xr = x + (size_t)b * NN;
    const float xt0 = xr[T + tid];
    const float xt1 = xr[T + 256 + tid];

    double acc0 = 0.0, acc1 = 0.0;
    const int cf16 = cf & ~15;

    // Fully-valid lags: groups of 16 -> 32 loads in flight; f32 partials -> f64 flush.
    for (int mo = 0; mo < cf16; mo += 16) {
        float g0a = 0.0f, g0b = 0.0f, g1a = 0.0f, g1b = 0.0f;
#pragma unroll
        for (int mi = 0; mi < 16; mi += 2) {
            const int   m0 = mo + mi, m1 = mo + mi + 1;
            const int   ja = __builtin_amdgcn_readlane(jv, m0);
            const float wa = readlane_f(wv, m0);
            const int   jb = __builtin_amdgcn_readlane(jv, m1);
            const float wb = readlane_f(wv, m1);
            const float* pa = xr + (T - ja);   // scalar base, vaddr = tid*4 shared
            const float* pb = xr + (T - jb);
            g0a = fmaf(xt0 - pa[tid],       wa, g0a);
            g1a = fmaf(xt1 - pa[tid + 256], wa, g1a);
            g0b = fmaf(xt0 - pb[tid],       wb, g0b);
            g1b = fmaf(xt1 - pb[tid + 256], wb, g1b);
        }
        acc0 += (double)(g0a + g0b);
        acc1 += (double)(g1a + g1b);
    }
    // Remainder of fully-valid lags.
    for (int m = cf16; m < cf; ++m) {
        const int   jj = __builtin_amdgcn_readlane(jv, m);
        const float w  = readlane_f(wv, m);
        const float* bp = xr + (T - jj);
        acc0 += (double)((xt0 - bp[tid]) * w);
        acc1 += (double)((xt1 - bp[tid + 256]) * w);
    }
    // Straddle lags (T < j <= T+511): per-lane masked clamp (~0-1 iters typical).
    for (int m = cf; m < cp; ++m) {
        const int   jj = __builtin_amdgcn_readlane(jv, m);
        const float w  = readlane_f(wv, m);
        const int d0 = T + tid - jj;
        const int d1 = d0 + 256;
        const float g0v = xr[(d0 < 0) ? 0 : d0];
        const float g1v = xr[(d1 < 0) ? 0 : d1];
        acc0 += (d0 >= 0) ? (double)((xt0 - g0v) * w) : 0.0;
        acc1 += (d1 >= 0) ? (double)((xt1 - g1v) * w) : 0.0;
    }

    float* __restrict__ orow = out + (size_t)b * NN;
    orow[T + tid]       = (float)acc0;
    orow[T + 256 + tid] = (float)acc1;
}

extern "C" void kernel_launch(void* const* d_in, const int* in_sizes, int n_in,
                              void* d_out, int out_size, void* d_ws, size_t ws_size,
                              hipStream_t stream) {
    const float* x     = (const float*)d_in[0];
    const float* loc   = (const float*)d_in[1];
    const float* scale = (const float*)d_in[2];
    const float* eps   = (const float*)d_in[3];
    const int*   lags  = (const int*)d_in[4];
    float* out = (float*)d_out;

    int*   js_ws = (int*)d_ws;
    float* ws_ws = (float*)((char*)d_ws + 256);

    setup_kernel<<<1, KK, 0, stream>>>(loc, scale, eps, lags, js_ws, ws_ws);
    frac_deriv_kernel<<<NBLK, TPB, 0, stream>>>(x, js_ws, ws_ws, out);
}